// Round 4
// baseline (771.839 us; speedup 1.0000x reference)
//
#include <hip/hip_runtime.h>

#define BLOCK 512
#define RPG   64      // rows per group: one row per lane

// Per u, all 64 lanes of a wave read the SAME 5 float4 weight slices -> LDS
// broadcast (unique 16B per ds_read_b128). Lane = row, wave = 4 output cols.
#define DO_U(u_, s_, vx_, vy_, vz_) { \
    const float4 wss  = *(const float4*)(&lds_w[0*2048 + (u_)*32 + lc]); \
    const float4 wvvs = *(const float4*)(&lds_w[1*2048 + (u_)*32 + lc]); \
    const float4 wsv  = *(const float4*)(&lds_w[2*2048 + (u_)*32 + lc]); \
    const float4 wvs  = *(const float4*)(&lds_w[3*2048 + (u_)*32 + lc]); \
    const float4 wvvv = *(const float4*)(&lds_w[4*2048 + (u_)*32 + lc]); \
    const float* wssf  = (const float*)&wss;  \
    const float* wvvsf = (const float*)&wvvs; \
    const float* wsvf  = (const float*)&wsv;  \
    const float* wvsf  = (const float*)&wvs;  \
    const float* wvvvf = (const float*)&wvvv; \
    _Pragma("unroll") \
    for (int j = 0; j < 4; ++j) { \
        yss[j]     += wssf[j]  * (s_);  \
        ysv[j]     += wsvf[j]  * (s_);  \
        yvvs[j][0] += wvvsf[j] * (vx_); \
        yvvs[j][1] += wvvsf[j] * (vy_); \
        yvvs[j][2] += wvvsf[j] * (vz_); \
        yvs[j][0]  += wvsf[j]  * (vx_); \
        yvs[j][1]  += wvsf[j]  * (vy_); \
        yvs[j][2]  += wvsf[j]  * (vz_); \
        yvvv[j][0] += wvvvf[j] * (vx_); \
        yvvv[j][1] += wvvvf[j] * (vy_); \
        yvvv[j][2] += wvvvf[j] * (vz_); \
    } \
}

#define DO_CHUNK(UB, S, V0, V1, V2) \
    DO_U((UB)+0, (S).x, (V0).x, (V0).y, (V0).z) \
    DO_U((UB)+1, (S).y, (V0).w, (V1).x, (V1).y) \
    DO_U((UB)+2, (S).z, (V1).z, (V1).w, (V2).x) \
    DO_U((UB)+3, (S).w, (V2).y, (V2).z, (V2).w)

__global__ __launch_bounds__(BLOCK) void tp_kernel(
    const float* __restrict__ x1, const float* __restrict__ x2,
    const float* __restrict__ w0, const float* __restrict__ w1,
    const float* __restrict__ w2, const float* __restrict__ w3,
    const float* __restrict__ w4,
    float* __restrict__ out, int n)
{
    __shared__ __align__(16) float lds_w[5 * 2048];   // 40 KB: this block's 32-col half

    const int t    = threadIdx.x;
    const int half = blockIdx.x & 1;          // which 32-col half of the output
    const int grp  = blockIdx.x >> 1;         // 64-row group
    const int wv   = t >> 6;                  // wave 0..7
    const int lane = t & 63;                  // row within group
    const int lc   = 4 * wv;                  // local col 0..28 (global: half*32 + lc)

    {   // ---- stage this half's weight columns (40 KB) ----
        const float* srcs[5] = {w0, w1, w2, w3, w4};
        #pragma unroll
        for (int m = 0; m < 5; ++m) {
            for (int i = t; i < 512; i += BLOCK) {
                const int u  = i >> 3;
                const int c4 = i & 7;
                *(float4*)(&lds_w[m * 2048 + u * 32 + 4 * c4]) =
                    *(const float4*)(srcs[m] + u * 64 + half * 32 + 4 * c4);
            }
        }
    }
    __syncthreads();   // only barrier in the kernel

    const int z    = grp * RPG + lane;
    const bool act = (z < n);
    const float* xrow = x1 + (size_t)(act ? z : 0) * 256;   // clamp: safe dummy row

    float yss[4], ysv[4], yvvs[4][3], yvs[4][3], yvvv[4][3];
    #pragma unroll
    for (int j = 0; j < 4; ++j) {
        yss[j] = 0.f; ysv[j] = 0.f;
        #pragma unroll
        for (int i = 0; i < 3; ++i) { yvvs[j][i] = 0.f; yvs[j][i] = 0.f; yvvv[j][i] = 0.f; }
    }

    // ---- stream x1 row in 4-u chunks, double-buffered in registers ----
    float4 sA  = *(const float4*)(xrow + 0);
    float4 vA0 = *(const float4*)(xrow + 64 + 0);
    float4 vA1 = *(const float4*)(xrow + 64 + 4);
    float4 vA2 = *(const float4*)(xrow + 64 + 8);
    float4 sB, vB0, vB1, vB2;

    #pragma unroll 1
    for (int c = 0; c < 16; c += 2) {
        sB  = *(const float4*)(xrow + 4 * (c + 1));
        vB0 = *(const float4*)(xrow + 64 + 12 * (c + 1) + 0);
        vB1 = *(const float4*)(xrow + 64 + 12 * (c + 1) + 4);
        vB2 = *(const float4*)(xrow + 64 + 12 * (c + 1) + 8);
        DO_CHUNK(4 * c, sA, vA0, vA1, vA2);
        if (c + 2 < 16) {
            sA  = *(const float4*)(xrow + 4 * (c + 2));
            vA0 = *(const float4*)(xrow + 64 + 12 * (c + 2) + 0);
            vA1 = *(const float4*)(xrow + 64 + 12 * (c + 2) + 4);
            vA2 = *(const float4*)(xrow + 64 + 12 * (c + 2) + 8);
        }
        DO_CHUNK(4 * c + 4, sB, vB0, vB1, vB2);
    }

    // ---- epilogue: fold in x2, write ----
    if (act) {
        const float a0  = 0.088388347648318447f;   // sqrt(1/(2*64))
        const float a1  = 0.072168783648703216f;   // sqrt(1/(3*64))
        const float is3 = 0.57735026918962576f;    // 1/sqrt(3)
        const float is2 = 0.70710678118654752f;    // 1/sqrt(2)
        const float4 x2v = *(const float4*)(x2 + (size_t)z * 4);   // coalesced: 16B/lane
        const float s2  = x2v.x;
        const float v2x = x2v.y;
        const float v2y = x2v.z;
        const float v2z = x2v.w;
        float* orow = out + (size_t)z * 256;
        const int gc = half * 32 + lc;
        alignas(16) float os[4];
        alignas(16) float ov[12];
        #pragma unroll
        for (int j = 0; j < 4; ++j) {
            os[j] = a0 * (yss[j] * s2
                  + is3 * (yvvs[j][0] * v2x + yvvs[j][1] * v2y + yvvs[j][2] * v2z));
            const float cx = yvvv[j][1] * v2z - yvvv[j][2] * v2y;
            const float cy = yvvv[j][2] * v2x - yvvv[j][0] * v2z;
            const float cz = yvvv[j][0] * v2y - yvvv[j][1] * v2x;
            ov[3*j+0] = a1 * (ysv[j] * v2x + yvs[j][0] * s2 + is2 * cx);
            ov[3*j+1] = a1 * (ysv[j] * v2y + yvs[j][1] * s2 + is2 * cy);
            ov[3*j+2] = a1 * (ysv[j] * v2z + yvs[j][2] * s2 + is2 * cz);
        }
        *(float4*)(orow + gc)              = *(float4*)os;
        *(float4*)(orow + 64 + 3*gc + 0)   = *(float4*)(ov + 0);
        *(float4*)(orow + 64 + 3*gc + 4)   = *(float4*)(ov + 4);
        *(float4*)(orow + 64 + 3*gc + 8)   = *(float4*)(ov + 8);
    }
}

extern "C" void kernel_launch(void* const* d_in, const int* in_sizes, int n_in,
                              void* d_out, int out_size, void* d_ws, size_t ws_size,
                              hipStream_t stream) {
    const float* x1 = (const float*)d_in[0];
    const float* x2 = (const float*)d_in[1];
    const float* w0 = (const float*)d_in[2];   // w_ss_s
    const float* w1 = (const float*)d_in[3];   // w_vv_s
    const float* w2 = (const float*)d_in[4];   // w_sv_v
    const float* w3 = (const float*)d_in[5];   // w_vs_v
    const float* w4 = (const float*)d_in[6];   // w_vv_v
    float* out = (float*)d_out;
    const int n = in_sizes[0] / 256;
    const int ngroups = (n + RPG - 1) / RPG;
    tp_kernel<<<2 * ngroups, BLOCK, 0, stream>>>(x1, x2, w0, w1, w2, w3, w4, out, n);
}